// Round 1
// baseline (341.891 us; speedup 1.0000x reference)
//
#include <hip/hip_runtime.h>
#include <cstdint>

typedef _Float16 half_t;
using half8 = __attribute__((ext_vector_type(8))) half_t;
using half4 = __attribute__((ext_vector_type(4))) half_t;
using f32x4 = __attribute__((ext_vector_type(4))) float;

#define LSEQ 2048
#define DM   1024
#define NH   16
#define DK   64

// ---------- helpers ----------
__device__ inline void gload_lds16(const void* g, void* l) {
    __builtin_amdgcn_global_load_lds(
        (const __attribute__((address_space(1))) uint32_t*)g,
        (__attribute__((address_space(3))) uint32_t*)l, 16, 0, 0);
}

__device__ inline uint32_t pkh(float a, float b) {
    half_t ha = (half_t)a, hb = (half_t)b;
    unsigned short ua = __builtin_bit_cast(unsigned short, ha);
    unsigned short ub = __builtin_bit_cast(unsigned short, hb);
    return (uint32_t)ua | ((uint32_t)ub << 16);
}

// ---------- 1. convert fp32 -> fp16 (q,k,v,Wq,Wk,Wv,Wo) ----------
__global__ __launch_bounds__(256) void cvt_kernel(
    const float* __restrict__ q, const float* __restrict__ k, const float* __restrict__ v,
    const float* __restrict__ wq, const float* __restrict__ wk,
    const float* __restrict__ wv, const float* __restrict__ wo,
    half_t* __restrict__ dst)
{
    long tid = (long)blockIdx.x * 256 + threadIdx.x;   // 4,194,304 threads
    long e = tid * 4;
    const float* src;
    long off;
    if (e < 12582912L) {            // 3 x 4M input elems
        int a = (int)(e >> 22);
        src = (a == 0) ? q : (a == 1) ? k : v;
        off = e & 4194303L;
    } else {                        // 4 x 1M weight elems
        long ew = e - 12582912L;
        int w = (int)(ew >> 20);
        src = (w == 0) ? wq : (w == 1) ? wk : (w == 2) ? wv : wo;
        off = ew & 1048575L;
    }
    float4 x = *(const float4*)(src + off);
    half4 o;
    o[0] = (half_t)x.x; o[1] = (half_t)x.y; o[2] = (half_t)x.z; o[3] = (half_t)x.w;
    *(half4*)(dst + e) = o;
}

// ---------- 2. RoPE cos/sin table [2048][32] ----------
__global__ __launch_bounds__(256) void rope_tab(float* __restrict__ cosT, float* __restrict__ sinT) {
    int tid = blockIdx.x * 256 + threadIdx.x;   // 65536
    int pos = tid >> 5;
    int j = tid & 31;
    float invf = powf(10000.0f, -(float)j / 32.0f);
    float a = (float)pos * invf;
    cosT[tid] = cosf(a);
    sinT[tid] = sinf(a);
}

// ---------- 3. GEMM  out[m][n] = sum_k A[m][k] * W[n][k] (+bias) ----------
// MODE 0: Q -> rope -> fp16 [4096][1024]
// MODE 1: K -> rope -> fp16 [4096][1024]
// MODE 2: V -> fp16 transposed [B*H][64][2048]
// MODE 3: out proj -> fp32 [4096][1024] (+bias)
template<int MODE>
__global__ __launch_bounds__(256) void gemm_k(
    const half_t* __restrict__ A, const half_t* __restrict__ Bw,
    const float* __restrict__ bias,
    half_t* __restrict__ o16, float* __restrict__ o32,
    const float* __restrict__ cosT, const float* __restrict__ sinT)
{
    __shared__ alignas(16) unsigned short sA[128 * 32];
    __shared__ alignas(16) unsigned short sB[128 * 32];
    const int tid = threadIdx.x;
    const int lane = tid & 63, wid = tid >> 6;
    const int g = lane >> 4, c = lane & 15;
    const int wr = wid >> 1, wc = wid & 1;
    const int row0 = blockIdx.y * 128, col0 = blockIdx.x * 128;

    f32x4 acc[4][4] = {};
    const int srow = lane >> 2;          // 0..15
    const int scol = (lane & 3) * 8;     // 0,8,16,24

    for (int k0 = 0; k0 < DM; k0 += 32) {
#pragma unroll
        for (int i = 0; i < 2; ++i) {
            int r = i * 64 + wid * 16;
            gload_lds16(A  + (long)(row0 + r + srow) * DM + k0 + scol, &sA[r * 32]);
            gload_lds16(Bw + (long)(col0 + r + srow) * DM + k0 + scol, &sB[r * 32]);
        }
        __syncthreads();
        half8 af[4], bf[4];
#pragma unroll
        for (int m = 0; m < 4; ++m)
            af[m] = *(const half8*)&sA[(wr * 64 + m * 16 + c) * 32 + g * 8];
#pragma unroll
        for (int n = 0; n < 4; ++n)
            bf[n] = *(const half8*)&sB[(wc * 64 + n * 16 + c) * 32 + g * 8];
#pragma unroll
        for (int m = 0; m < 4; ++m)
#pragma unroll
            for (int n = 0; n < 4; ++n)
                acc[m][n] = __builtin_amdgcn_mfma_f32_16x16x32_f16(af[m], bf[n], acc[m][n], 0, 0, 0);
        __syncthreads();
    }

    if constexpr (MODE == 3) {
#pragma unroll
        for (int n = 0; n < 4; ++n) {
            int col = col0 + wc * 64 + n * 16 + c;
            float bv = bias[col];
#pragma unroll
            for (int m = 0; m < 4; ++m)
#pragma unroll
                for (int r = 0; r < 4; ++r) {
                    int row = row0 + wr * 64 + m * 16 + g * 4 + r;
                    o32[(long)row * DM + col] = acc[m][n][r] + bv;
                }
        }
    } else if constexpr (MODE == 2) {
        int h = blockIdx.x * 2 + wc;
#pragma unroll
        for (int n = 0; n < 4; ++n) {
            int col = col0 + wc * 64 + n * 16 + c;
            float bv = bias[col];
            int d = n * 16 + c;
#pragma unroll
            for (int m = 0; m < 4; ++m)
#pragma unroll
                for (int r = 0; r < 4; ++r) {
                    int row = row0 + wr * 64 + m * 16 + g * 4 + r;
                    int b = row >> 11, pos = row & 2047;
                    o16[((long)(b * NH + h) * 64 + d) * LSEQ + pos] = (half_t)(acc[m][n][r] + bv);
                }
        }
    } else {  // Q / K with RoPE
#pragma unroll
        for (int np = 0; np < 2; ++np) {
            int col1 = col0 + wc * 64 + np * 16 + c;
            int j = np * 16 + c;           // 0..31
            float b1 = bias[col1], b2 = bias[col1 + 32];
#pragma unroll
            for (int m = 0; m < 4; ++m)
#pragma unroll
                for (int r = 0; r < 4; ++r) {
                    int row = row0 + wr * 64 + m * 16 + g * 4 + r;
                    int pos = row & 2047;
                    float cv = cosT[pos * 32 + j], sv = sinT[pos * 32 + j];
                    float x1 = acc[m][np][r] + b1;
                    float x2 = acc[m][np + 2][r] + b2;
                    o16[(long)row * DM + col1]      = (half_t)(x1 * cv - x2 * sv);
                    o16[(long)row * DM + col1 + 32] = (half_t)(x2 * cv + x1 * sv);
                }
        }
    }
}

// ---------- 4. causal flash attention ----------
// grid (L/64, B*H); 4 waves/block; wave owns 16 q-rows.
// S^T = K*Q^T via mfma (lane: key=g*4+r rows, q=c cols); online softmax per q;
// P^T repacked via 8 shuffles -> B-operand of PV mfma; O^T accumulated.
__global__ __launch_bounds__(256) void attn_k(
    const half_t* __restrict__ QR, const half_t* __restrict__ KR,
    const half_t* __restrict__ VT, half_t* __restrict__ AO)
{
    const int tid = threadIdx.x, lane = tid & 63, wid = tid >> 6;
    const int g = lane >> 4, c = lane & 15;
    const int q0 = blockIdx.x * 64 + wid * 16;
    const int bh = blockIdx.y, b = bh >> 4, h = bh & 15;

    const long qrow = (long)(b * LSEQ + q0 + c) * DM + h * DK;
    half8 qf0 = *(const half8*)&QR[qrow + 0  + g * 8];
    half8 qf1 = *(const half8*)&QR[qrow + 32 + g * 8];

    f32x4 accO[4] = {};
    float mold = -INFINITY, lsum = 0.0f;
    const int q = q0 + c;
    const int kend = q0 + 16;
    const long vbase = (long)bh * 64 * LSEQ;

    for (int k0 = 0; k0 < kend; k0 += 32) {
        const long kbase = (long)(b * LSEQ + k0) * DM + h * DK;
        f32x4 s0 = {}, s1 = {};
        half8 kf;
        kf = *(const half8*)&KR[kbase + (long)c * DM + g * 8];
        s0 = __builtin_amdgcn_mfma_f32_16x16x32_f16(kf, qf0, s0, 0, 0, 0);
        kf = *(const half8*)&KR[kbase + (long)c * DM + 32 + g * 8];
        s0 = __builtin_amdgcn_mfma_f32_16x16x32_f16(kf, qf1, s0, 0, 0, 0);
        kf = *(const half8*)&KR[kbase + (long)(16 + c) * DM + g * 8];
        s1 = __builtin_amdgcn_mfma_f32_16x16x32_f16(kf, qf0, s1, 0, 0, 0);
        kf = *(const half8*)&KR[kbase + (long)(16 + c) * DM + 32 + g * 8];
        s1 = __builtin_amdgcn_mfma_f32_16x16x32_f16(kf, qf1, s1, 0, 0, 0);

        float sv[8];
#pragma unroll
        for (int r = 0; r < 4; ++r) {
            int key0 = k0 + g * 4 + r;
            int key1 = key0 + 16;
            sv[r]     = (key0 <= q) ? s0[r] * 0.125f : -INFINITY;
            sv[4 + r] = (key1 <= q) ? s1[r] * 0.125f : -INFINITY;
        }
        float tm = sv[0];
#pragma unroll
        for (int i = 1; i < 8; ++i) tm = fmaxf(tm, sv[i]);
        tm = fmaxf(tm, __shfl_xor(tm, 16, 64));
        tm = fmaxf(tm, __shfl_xor(tm, 32, 64));
        float mnew = fmaxf(mold, tm);
        float resc = expf(mold - mnew);

        float p[8], ps = 0.0f;
#pragma unroll
        for (int i = 0; i < 8; ++i) { p[i] = expf(sv[i] - mnew); ps += p[i]; }
        ps += __shfl_xor(ps, 16, 64);
        ps += __shfl_xor(ps, 32, 64);
        lsum = lsum * resc + ps;
#pragma unroll
        for (int dt = 0; dt < 4; ++dt) accO[dt] *= resc;

        uint32_t w0 = pkh(p[0], p[1]), w1 = pkh(p[2], p[3]);
        uint32_t w2 = pkh(p[4], p[5]), w3 = pkh(p[6], p[7]);
        union { half8 h8; uint32_t u[4]; } bfr;
#pragma unroll
        for (int t = 0; t < 4; ++t) {
            int srcl = ((g & 1) * 2 + (t >> 1)) * 16 + c;
            uint32_t lo = (uint32_t)__shfl((int)((t & 1) ? w1 : w0), srcl, 64);
            uint32_t hi = (uint32_t)__shfl((int)((t & 1) ? w3 : w2), srcl, 64);
            bfr.u[t] = (lane < 32) ? lo : hi;
        }
#pragma unroll
        for (int dt = 0; dt < 4; ++dt) {
            half8 vf = *(const half8*)&VT[vbase + (long)(dt * 16 + c) * LSEQ + k0 + g * 8];
            accO[dt] = __builtin_amdgcn_mfma_f32_16x16x32_f16(vf, bfr.h8, accO[dt], 0, 0, 0);
        }
        mold = mnew;
    }

    float inv = 1.0f / lsum;
    const long obase = (long)(b * LSEQ + q0 + c) * DM + h * DK;
#pragma unroll
    for (int dt = 0; dt < 4; ++dt)
#pragma unroll
        for (int r = 0; r < 4; ++r)
            AO[obase + dt * 16 + g * 4 + r] = (half_t)(accO[dt][r] * inv);
}

// ---------- launch ----------
extern "C" void kernel_launch(void* const* d_in, const int* in_sizes, int n_in,
                              void* d_out, int out_size, void* d_ws, size_t ws_size,
                              hipStream_t stream) {
    const float* q  = (const float*)d_in[0];
    const float* k  = (const float*)d_in[1];
    const float* v  = (const float*)d_in[2];
    // d_in[3] = mask (causal, fixed) -- unused
    const float* wq = (const float*)d_in[4];
    const float* bq = (const float*)d_in[5];
    const float* wk = (const float*)d_in[6];
    const float* bk = (const float*)d_in[7];
    const float* wv = (const float*)d_in[8];
    const float* bv = (const float*)d_in[9];
    const float* wo = (const float*)d_in[10];
    const float* bo = (const float*)d_in[11];

    uint8_t* wsb = (uint8_t*)d_ws;
    half_t* XH = (half_t*)wsb;                       // 3 x 4194304 halfs
    half_t* WH = XH + 12582912L;                     // 4 x 1048576 halfs
    float*  COS = (float*)(wsb + 33554432L);         // 2048*32 f32
    float*  SIN = (float*)(wsb + 33816576L);
    half_t* QR = (half_t*)(wsb + 34078720L);         // [4096][1024] f16
    half_t* KR = (half_t*)(wsb + 42467328L);
    half_t* VT = (half_t*)(wsb + 50855936L);         // [32][64][2048] f16
    half_t* AO = (half_t*)(wsb + 59244544L);         // [4096][1024] f16

    cvt_kernel<<<16384, 256, 0, stream>>>(q, k, v, wq, wk, wv, wo, XH);
    rope_tab<<<256, 256, 0, stream>>>(COS, SIN);

    dim3 ggrid(8, 32);
    gemm_k<0><<<ggrid, 256, 0, stream>>>(XH,             WH,             bq, QR, nullptr, COS, SIN);
    gemm_k<1><<<ggrid, 256, 0, stream>>>(XH + 4194304L,  WH + 1048576L,  bk, KR, nullptr, COS, SIN);
    gemm_k<2><<<ggrid, 256, 0, stream>>>(XH + 8388608L,  WH + 2097152L,  bv, VT, nullptr, COS, SIN);

    attn_k<<<dim3(32, 32), 256, 0, stream>>>(QR, KR, VT, AO);

    gemm_k<3><<<ggrid, 256, 0, stream>>>(AO, WH + 3145728L, bo, nullptr, (float*)d_out, COS, SIN);
}

// Round 2
// 202.128 us; speedup vs baseline: 1.6915x; 1.6915x over previous
//
#include <hip/hip_runtime.h>
#include <cstdint>

typedef _Float16 half_t;
using half8 = __attribute__((ext_vector_type(8))) half_t;
using half4 = __attribute__((ext_vector_type(4))) half_t;
using f32x4 = __attribute__((ext_vector_type(4))) float;
using f32x16 = __attribute__((ext_vector_type(16))) float;

#define LSEQ 2048
#define DM   1024
#define NH   16
#define DK   64

// ---------- helpers ----------
__device__ inline void gload_lds16(const void* g, void* l) {
    __builtin_amdgcn_global_load_lds(
        (const __attribute__((address_space(1))) uint32_t*)g,
        (__attribute__((address_space(3))) uint32_t*)l, 16, 0, 0);
}

__device__ inline uint32_t pkh(float a, float b) {
    half_t ha = (half_t)a, hb = (half_t)b;
    unsigned short ua = __builtin_bit_cast(unsigned short, ha);
    unsigned short ub = __builtin_bit_cast(unsigned short, hb);
    return (uint32_t)ua | ((uint32_t)ub << 16);
}

// ---------- 1. convert fp32 -> fp16 (q,k,v,Wq,Wk,Wv,Wo) ----------
__global__ __launch_bounds__(256) void cvt_kernel(
    const float* __restrict__ q, const float* __restrict__ k, const float* __restrict__ v,
    const float* __restrict__ wq, const float* __restrict__ wk,
    const float* __restrict__ wv, const float* __restrict__ wo,
    half_t* __restrict__ dst)
{
    long tid = (long)blockIdx.x * 256 + threadIdx.x;
    long e = tid * 4;
    const float* src;
    long off;
    if (e < 12582912L) {
        int a = (int)(e >> 22);
        src = (a == 0) ? q : (a == 1) ? k : v;
        off = e & 4194303L;
    } else {
        long ew = e - 12582912L;
        int w = (int)(ew >> 20);
        src = (w == 0) ? wq : (w == 1) ? wk : (w == 2) ? wv : wo;
        off = ew & 1048575L;
    }
    float4 x = *(const float4*)(src + off);
    half4 o;
    o[0] = (half_t)x.x; o[1] = (half_t)x.y; o[2] = (half_t)x.z; o[3] = (half_t)x.w;
    *(half4*)(dst + e) = o;
}

// ---------- 2. RoPE cos/sin table [2048][32] ----------
__global__ __launch_bounds__(256) void rope_tab(float* __restrict__ cosT, float* __restrict__ sinT) {
    int tid = blockIdx.x * 256 + threadIdx.x;
    int pos = tid >> 5;
    int j = tid & 31;
    float invf = powf(10000.0f, -(float)j / 32.0f);
    float a = (float)pos * invf;
    cosT[tid] = cosf(a);
    sinT[tid] = sinf(a);
}

// ---------- 3. GEMM  out[m][n] = sum_k A[m][k] * W[n][k] (+bias) ----------
// MODE 0: Q -> rope -> scaled f16 per-head layout QH[bh][pos][64]
// MODE 1: K -> rope -> f16 per-head layout KH[bh][pos][64]
// MODE 2: V -> f16 transposed VT[bh][64][2048]
// MODE 3: out proj -> fp32 [4096][1024] (+bias)
template<int MODE>
__global__ __launch_bounds__(256) void gemm_k(
    const half_t* __restrict__ A, const half_t* __restrict__ Bw,
    const float* __restrict__ bias,
    half_t* __restrict__ o16, float* __restrict__ o32,
    const float* __restrict__ cosT, const float* __restrict__ sinT)
{
    __shared__ alignas(16) unsigned short sA[128 * 32];
    __shared__ alignas(16) unsigned short sB[128 * 32];
    const int tid = threadIdx.x;
    const int lane = tid & 63, wid = tid >> 6;
    const int g = lane >> 4, c = lane & 15;
    const int wr = wid >> 1, wc = wid & 1;
    const int row0 = blockIdx.y * 128, col0 = blockIdx.x * 128;

    f32x4 acc[4][4] = {};
    const int srow = lane >> 2;
    const int scol = (lane & 3) * 8;

    for (int k0 = 0; k0 < DM; k0 += 32) {
#pragma unroll
        for (int i = 0; i < 2; ++i) {
            int r = i * 64 + wid * 16;
            gload_lds16(A  + (long)(row0 + r + srow) * DM + k0 + scol, &sA[r * 32]);
            gload_lds16(Bw + (long)(col0 + r + srow) * DM + k0 + scol, &sB[r * 32]);
        }
        __syncthreads();
        half8 af[4], bf[4];
#pragma unroll
        for (int m = 0; m < 4; ++m)
            af[m] = *(const half8*)&sA[(wr * 64 + m * 16 + c) * 32 + g * 8];
#pragma unroll
        for (int n = 0; n < 4; ++n)
            bf[n] = *(const half8*)&sB[(wc * 64 + n * 16 + c) * 32 + g * 8];
#pragma unroll
        for (int m = 0; m < 4; ++m)
#pragma unroll
            for (int n = 0; n < 4; ++n)
                acc[m][n] = __builtin_amdgcn_mfma_f32_16x16x32_f16(af[m], bf[n], acc[m][n], 0, 0, 0);
        __syncthreads();
    }

    if constexpr (MODE == 3) {
#pragma unroll
        for (int n = 0; n < 4; ++n) {
            int col = col0 + wc * 64 + n * 16 + c;
            float bv = bias[col];
#pragma unroll
            for (int m = 0; m < 4; ++m)
#pragma unroll
                for (int r = 0; r < 4; ++r) {
                    int row = row0 + wr * 64 + m * 16 + g * 4 + r;
                    o32[(long)row * DM + col] = acc[m][n][r] + bv;
                }
        }
    } else if constexpr (MODE == 2) {
        int h = blockIdx.x * 2 + wc;
#pragma unroll
        for (int n = 0; n < 4; ++n) {
            int col = col0 + wc * 64 + n * 16 + c;
            float bv = bias[col];
            int d = n * 16 + c;
#pragma unroll
            for (int m = 0; m < 4; ++m)
#pragma unroll
                for (int r = 0; r < 4; ++r) {
                    int row = row0 + wr * 64 + m * 16 + g * 4 + r;
                    int b = row >> 11, pos = row & 2047;
                    o16[((long)(b * NH + h) * 64 + d) * LSEQ + pos] = (half_t)(acc[m][n][r] + bv);
                }
        }
    } else {  // Q / K with RoPE -> [bh][pos][64]; Q additionally scaled
        const float SC = (MODE == 0) ? 0.125f * 1.44269504f : 1.0f;
#pragma unroll
        for (int np = 0; np < 2; ++np) {
            int col1 = col0 + wc * 64 + np * 16 + c;
            int h = col1 >> 6;
            int d1 = np * 16 + c;          // 0..31
            float b1 = bias[col1], b2 = bias[col1 + 32];
#pragma unroll
            for (int m = 0; m < 4; ++m)
#pragma unroll
                for (int r = 0; r < 4; ++r) {
                    int row = row0 + wr * 64 + m * 16 + g * 4 + r;
                    int b = row >> 11, pos = row & 2047;
                    float cv = cosT[pos * 32 + d1], sv = sinT[pos * 32 + d1];
                    float x1 = acc[m][np][r] + b1;
                    float x2 = acc[m][np + 2][r] + b2;
                    long obase = ((long)((b * NH + h) * LSEQ + pos)) * 64;
                    o16[obase + d1]      = (half_t)((x1 * cv - x2 * sv) * SC);
                    o16[obase + d1 + 32] = (half_t)((x2 * cv + x1 * sv) * SC);
                }
        }
    }
}

// ---------- 4. causal flash attention, 32x32x16 MFMA ----------
// One wave per (q-tile of 32, bh). 2048 waves, big tiles first.
// S^T[key][q] = mfma(K, Q): q = lane&31, 16 keys in regs (crow pattern).
// Softmax in-register per q-column; one xor32 shuffle per reduce.
// P^T repacked to PV B-operand via 4 xor32 shuffles per 32 keys.
// O^T[d][q] accumulated via mfma(V^T, P).
__global__ __launch_bounds__(256) void attn_k(
    const half_t* __restrict__ QH, const half_t* __restrict__ KH,
    const half_t* __restrict__ VT, half_t* __restrict__ AO)
{
    const int lane = threadIdx.x & 63, wid = threadIdx.x >> 6;
    const int wg = blockIdx.x * 4 + wid;      // 0..2047
    const int t  = 63 - (wg >> 5);            // big q-tiles first
    const int bh = wg & 31;
    const int qc = lane & 31, hi = lane >> 5;
    const int b = bh >> 4, h = bh & 15;

    const half_t* Qb = QH + ((long)bh * LSEQ + t * 32) * 64;
    const half_t* Kb = KH + (long)bh * LSEQ * 64;
    const half_t* Vb = VT + (long)bh * 64 * LSEQ;

    half8 qf[4];
#pragma unroll
    for (int dc = 0; dc < 4; ++dc)
        qf[dc] = *(const half8*)(Qb + qc * 64 + dc * 16 + hi * 8);

    f32x16 acc[2] = {};
    float m = -INFINITY, l = 0.0f;

    union PB { uint32_t u[4]; half8 h; };

    auto step = [&](int k0, bool domask) {
        // ---- loads (issued up front; V used late in the step) ----
        half8 kf0[4], kf1[4], vf[2][4];
        const half_t* K0 = Kb + (long)(k0 + qc) * 64;
#pragma unroll
        for (int dc = 0; dc < 4; ++dc) {
            kf0[dc] = *(const half8*)(K0 + dc * 16 + hi * 8);
            kf1[dc] = *(const half8*)(K0 + 32 * 64 + dc * 16 + hi * 8);
        }
#pragma unroll
        for (int dt = 0; dt < 2; ++dt)
#pragma unroll
            for (int kc = 0; kc < 4; ++kc)
                vf[dt][kc] = *(const half8*)(Vb + (long)(dt * 32 + qc) * LSEQ + k0 + kc * 16 + hi * 8);

        // ---- QK^T ----
        f32x16 s0 = {}, s1 = {};
#pragma unroll
        for (int dc = 0; dc < 4; ++dc) s0 = __builtin_amdgcn_mfma_f32_32x32x16_f16(kf0[dc], qf[dc], s0, 0, 0, 0);
#pragma unroll
        for (int dc = 0; dc < 4; ++dc) s1 = __builtin_amdgcn_mfma_f32_32x32x16_f16(kf1[dc], qf[dc], s1, 0, 0, 0);

        if (domask) {
            int qg = t * 32 + qc;
#pragma unroll
            for (int r = 0; r < 16; ++r) {
                int crow = (r & 3) + 8 * (r >> 2) + 4 * hi;
                if (k0 + crow > qg)      s0[r] = -INFINITY;
                if (k0 + 32 + crow > qg) s1[r] = -INFINITY;
            }
        }

        // ---- online softmax (per q-column; keys split lane/lane^32) ----
        float mx[8];
#pragma unroll
        for (int r = 0; r < 8; ++r)
            mx[r] = fmaxf(fmaxf(s0[r], s0[8 + r]), fmaxf(s1[r], s1[8 + r]));
#pragma unroll
        for (int st = 4; st >= 1; st >>= 1)
#pragma unroll
            for (int r = 0; r < 4; ++r)
                if (r < st) mx[r] = fmaxf(mx[r], mx[r + st]);
        float pm = fmaxf(mx[0], __shfl_xor(mx[0], 32, 64));
        float mn = fmaxf(m, pm);
        float sc = exp2f(m - mn);
#pragma unroll
        for (int r = 0; r < 16; ++r) {
            s0[r] = exp2f(s0[r] - mn);
            s1[r] = exp2f(s1[r] - mn);
        }
        float sm[8];
#pragma unroll
        for (int r = 0; r < 8; ++r) sm[r] = (s0[r] + s0[8 + r]) + (s1[r] + s1[8 + r]);
#pragma unroll
        for (int st = 4; st >= 1; st >>= 1)
#pragma unroll
            for (int r = 0; r < 4; ++r)
                if (r < st) sm[r] += sm[r + st];
        float ls = sm[0] + __shfl_xor(sm[0], 32, 64);
        l = l * sc + ls;
        m = mn;
#pragma unroll
        for (int r = 0; r < 16; ++r) { acc[0][r] *= sc; acc[1][r] *= sc; }

        // ---- pack P^T -> PV B-operand (4 shuffles per 32-key slot) ----
        uint32_t A0[8], A1[8];
#pragma unroll
        for (int i = 0; i < 8; ++i) {
            A0[i] = pkh(s0[2 * i], s0[2 * i + 1]);
            A1[i] = pkh(s1[2 * i], s1[2 * i + 1]);
        }
        bool hb = (hi != 0);
        uint32_t U0 = (uint32_t)__shfl_xor((int)(hb ? A0[0] : A0[2]), 32, 64);
        uint32_t U1 = (uint32_t)__shfl_xor((int)(hb ? A0[1] : A0[3]), 32, 64);
        uint32_t U2 = (uint32_t)__shfl_xor((int)(hb ? A0[4] : A0[6]), 32, 64);
        uint32_t U3 = (uint32_t)__shfl_xor((int)(hb ? A0[5] : A0[7]), 32, 64);
        uint32_t U4 = (uint32_t)__shfl_xor((int)(hb ? A1[0] : A1[2]), 32, 64);
        uint32_t U5 = (uint32_t)__shfl_xor((int)(hb ? A1[1] : A1[3]), 32, 64);
        uint32_t U6 = (uint32_t)__shfl_xor((int)(hb ? A1[4] : A1[6]), 32, 64);
        uint32_t U7 = (uint32_t)__shfl_xor((int)(hb ? A1[5] : A1[7]), 32, 64);
        PB B00, B01, B10, B11;
        B00.u[0] = hb ? U0 : A0[0]; B00.u[1] = hb ? U1 : A0[1];
        B00.u[2] = hb ? A0[2] : U0; B00.u[3] = hb ? A0[3] : U1;
        B01.u[0] = hb ? U2 : A0[4]; B01.u[1] = hb ? U3 : A0[5];
        B01.u[2] = hb ? A0[6] : U2; B01.u[3] = hb ? A0[7] : U3;
        B10.u[0] = hb ? U4 : A1[0]; B10.u[1] = hb ? U5 : A1[1];
        B10.u[2] = hb ? A1[2] : U4; B10.u[3] = hb ? A1[3] : U5;
        B11.u[0] = hb ? U6 : A1[4]; B11.u[1] = hb ? U7 : A1[5];
        B11.u[2] = hb ? A1[6] : U6; B11.u[3] = hb ? A1[7] : U7;

        // ---- PV: O^T[d][q] += V^T * P ----
#pragma unroll
        for (int dt = 0; dt < 2; ++dt) {
            acc[dt] = __builtin_amdgcn_mfma_f32_32x32x16_f16(vf[dt][0], B00.h, acc[dt], 0, 0, 0);
            acc[dt] = __builtin_amdgcn_mfma_f32_32x32x16_f16(vf[dt][1], B01.h, acc[dt], 0, 0, 0);
            acc[dt] = __builtin_amdgcn_mfma_f32_32x32x16_f16(vf[dt][2], B10.h, acc[dt], 0, 0, 0);
            acc[dt] = __builtin_amdgcn_mfma_f32_32x32x16_f16(vf[dt][3], B11.h, acc[dt], 0, 0, 0);
        }
    };

    const int F = (32 * t + 1) >> 6;   // fully-unmasked 64-key steps
    for (int k0 = 0; k0 < 64 * F; k0 += 64) step(k0, false);
    step(64 * F, true);                // single masked tail step

    float inv = 1.0f / l;
    long obase = ((long)(b * LSEQ + t * 32 + qc)) * DM + h * 64;
#pragma unroll
    for (int dt = 0; dt < 2; ++dt)
#pragma unroll
        for (int rg = 0; rg < 4; ++rg) {
            half4 o;
#pragma unroll
            for (int e = 0; e < 4; ++e) o[e] = (half_t)(acc[dt][4 * rg + e] * inv);
            *(half4*)(AO + obase + dt * 32 + 8 * rg + 4 * hi) = o;
        }
}

// ---------- launch ----------
extern "C" void kernel_launch(void* const* d_in, const int* in_sizes, int n_in,
                              void* d_out, int out_size, void* d_ws, size_t ws_size,
                              hipStream_t stream) {
    const float* q  = (const float*)d_in[0];
    const float* k  = (const float*)d_in[1];
    const float* v  = (const float*)d_in[2];
    const float* wq = (const float*)d_in[4];
    const float* bq = (const float*)d_in[5];
    const float* wk = (const float*)d_in[6];
    const float* bk = (const float*)d_in[7];
    const float* wv = (const float*)d_in[8];
    const float* bv = (const float*)d_in[9];
    const float* wo = (const float*)d_in[10];
    const float* bo = (const float*)d_in[11];

    uint8_t* wsb = (uint8_t*)d_ws;
    half_t* XH = (half_t*)wsb;                       // 3 x 4194304 halfs
    half_t* WH = XH + 12582912L;                     // 4 x 1048576 halfs
    float*  COS = (float*)(wsb + 33554432L);         // 2048*32 f32
    float*  SIN = (float*)(wsb + 33816576L);
    half_t* QH = (half_t*)(wsb + 34078720L);         // [32][2048][64] f16 (scaled)
    half_t* KH = (half_t*)(wsb + 42467328L);         // [32][2048][64] f16
    half_t* VT = (half_t*)(wsb + 50855936L);         // [32][64][2048] f16
    half_t* AO = (half_t*)(wsb + 59244544L);         // [4096][1024] f16

    cvt_kernel<<<16384, 256, 0, stream>>>(q, k, v, wq, wk, wv, wo, XH);
    rope_tab<<<256, 256, 0, stream>>>(COS, SIN);

    dim3 ggrid(8, 32);
    gemm_k<0><<<ggrid, 256, 0, stream>>>(XH,             WH,             bq, QH, nullptr, COS, SIN);
    gemm_k<1><<<ggrid, 256, 0, stream>>>(XH + 4194304L,  WH + 1048576L,  bk, KH, nullptr, COS, SIN);
    gemm_k<2><<<ggrid, 256, 0, stream>>>(XH + 8388608L,  WH + 2097152L,  bv, VT, nullptr, COS, SIN);

    attn_k<<<512, 256, 0, stream>>>(QH, KH, VT, AO);

    gemm_k<3><<<ggrid, 256, 0, stream>>>(AO, WH + 3145728L, bo, nullptr, (float*)d_out, COS, SIN);
}

// Round 3
// 181.138 us; speedup vs baseline: 1.8875x; 1.1159x over previous
//
#include <hip/hip_runtime.h>
#include <cstdint>

typedef _Float16 half_t;
using half8 = __attribute__((ext_vector_type(8))) half_t;
using half4 = __attribute__((ext_vector_type(4))) half_t;
using f32x4 = __attribute__((ext_vector_type(4))) float;
using f32x16 = __attribute__((ext_vector_type(16))) float;

#define LSEQ 2048
#define DM   1024
#define NH   16
#define DK   64

// ---------- helpers ----------
__device__ inline void gload_lds16(const void* g, void* l) {
    __builtin_amdgcn_global_load_lds(
        (const __attribute__((address_space(1))) uint32_t*)g,
        (__attribute__((address_space(3))) uint32_t*)l, 16, 0, 0);
}

__device__ inline uint32_t pkh(float a, float b) {
    half_t ha = (half_t)a, hb = (half_t)b;
    unsigned short ua = __builtin_bit_cast(unsigned short, ha);
    unsigned short ub = __builtin_bit_cast(unsigned short, hb);
    return (uint32_t)ua | ((uint32_t)ub << 16);
}

// ---------- 1. convert fp32 -> fp16 (q,k,v,Wq,Wk,Wv,Wo) ----------
__global__ __launch_bounds__(256) void cvt_kernel(
    const float* __restrict__ q, const float* __restrict__ k, const float* __restrict__ v,
    const float* __restrict__ wq, const float* __restrict__ wk,
    const float* __restrict__ wv, const float* __restrict__ wo,
    half_t* __restrict__ dst)
{
    long tid = (long)blockIdx.x * 256 + threadIdx.x;
    long e = tid * 4;
    const float* src;
    long off;
    if (e < 12582912L) {
        int a = (int)(e >> 22);
        src = (a == 0) ? q : (a == 1) ? k : v;
        off = e & 4194303L;
    } else {
        long ew = e - 12582912L;
        int w = (int)(ew >> 20);
        src = (w == 0) ? wq : (w == 1) ? wk : (w == 2) ? wv : wo;
        off = ew & 1048575L;
    }
    float4 x = *(const float4*)(src + off);
    half4 o;
    o[0] = (half_t)x.x; o[1] = (half_t)x.y; o[2] = (half_t)x.z; o[3] = (half_t)x.w;
    *(half4*)(dst + e) = o;
}

// ---------- 2. RoPE cos/sin table [2048][32] ----------
__global__ __launch_bounds__(256) void rope_tab(float* __restrict__ cosT, float* __restrict__ sinT) {
    int tid = blockIdx.x * 256 + threadIdx.x;
    int pos = tid >> 5;
    int j = tid & 31;
    float invf = powf(10000.0f, -(float)j / 32.0f);
    float a = (float)pos * invf;
    cosT[tid] = cosf(a);
    sinT[tid] = sinf(a);
}

// ---------- 3. GEMM  out[m][n] = sum_k A[m][k] * W[n][k] (+bias) ----------
// MODE 0: Q -> rope -> scaled f16 per-head layout QH[bh][pos][64]
// MODE 1: K -> rope -> f16 per-head layout KH[bh][pos][64]
// MODE 2: V -> f16 transposed VT[bh][64][2048]
// MODE 3: out proj -> fp32 [4096][1024] (+bias)
template<int MODE>
__global__ __launch_bounds__(256) void gemm_k(
    const half_t* __restrict__ A, const half_t* __restrict__ Bw,
    const float* __restrict__ bias,
    half_t* __restrict__ o16, float* __restrict__ o32,
    const float* __restrict__ cosT, const float* __restrict__ sinT)
{
    __shared__ alignas(16) unsigned short sA[128 * 32];
    __shared__ alignas(16) unsigned short sB[128 * 32];
    const int tid = threadIdx.x;
    const int lane = tid & 63, wid = tid >> 6;
    const int g = lane >> 4, c = lane & 15;
    const int wr = wid >> 1, wc = wid & 1;
    const int row0 = blockIdx.y * 128, col0 = blockIdx.x * 128;

    f32x4 acc[4][4] = {};
    const int srow = lane >> 2;
    const int scol = (lane & 3) * 8;

    for (int k0 = 0; k0 < DM; k0 += 32) {
#pragma unroll
        for (int i = 0; i < 2; ++i) {
            int r = i * 64 + wid * 16;
            gload_lds16(A  + (long)(row0 + r + srow) * DM + k0 + scol, &sA[r * 32]);
            gload_lds16(Bw + (long)(col0 + r + srow) * DM + k0 + scol, &sB[r * 32]);
        }
        __syncthreads();
        half8 af[4], bf[4];
#pragma unroll
        for (int m = 0; m < 4; ++m)
            af[m] = *(const half8*)&sA[(wr * 64 + m * 16 + c) * 32 + g * 8];
#pragma unroll
        for (int n = 0; n < 4; ++n)
            bf[n] = *(const half8*)&sB[(wc * 64 + n * 16 + c) * 32 + g * 8];
#pragma unroll
        for (int m = 0; m < 4; ++m)
#pragma unroll
            for (int n = 0; n < 4; ++n)
                acc[m][n] = __builtin_amdgcn_mfma_f32_16x16x32_f16(af[m], bf[n], acc[m][n], 0, 0, 0);
        __syncthreads();
    }

    if constexpr (MODE == 3) {
#pragma unroll
        for (int n = 0; n < 4; ++n) {
            int col = col0 + wc * 64 + n * 16 + c;
            float bv = bias[col];
#pragma unroll
            for (int m = 0; m < 4; ++m)
#pragma unroll
                for (int r = 0; r < 4; ++r) {
                    int row = row0 + wr * 64 + m * 16 + g * 4 + r;
                    o32[(long)row * DM + col] = acc[m][n][r] + bv;
                }
        }
    } else if constexpr (MODE == 2) {
        int h = blockIdx.x * 2 + wc;
#pragma unroll
        for (int n = 0; n < 4; ++n) {
            int col = col0 + wc * 64 + n * 16 + c;
            float bv = bias[col];
            int d = n * 16 + c;
#pragma unroll
            for (int m = 0; m < 4; ++m)
#pragma unroll
                for (int r = 0; r < 4; ++r) {
                    int row = row0 + wr * 64 + m * 16 + g * 4 + r;
                    int b = row >> 11, pos = row & 2047;
                    o16[((long)(b * NH + h) * 64 + d) * LSEQ + pos] = (half_t)(acc[m][n][r] + bv);
                }
        }
    } else {  // Q / K with RoPE -> [bh][pos][64]; Q additionally scaled
        const float SC = (MODE == 0) ? 0.125f * 1.44269504f : 1.0f;
#pragma unroll
        for (int np = 0; np < 2; ++np) {
            int col1 = col0 + wc * 64 + np * 16 + c;
            int h = col1 >> 6;
            int d1 = np * 16 + c;          // 0..31
            float b1 = bias[col1], b2 = bias[col1 + 32];
#pragma unroll
            for (int m = 0; m < 4; ++m)
#pragma unroll
                for (int r = 0; r < 4; ++r) {
                    int row = row0 + wr * 64 + m * 16 + g * 4 + r;
                    int b = row >> 11, pos = row & 2047;
                    float cv = cosT[pos * 32 + d1], sv = sinT[pos * 32 + d1];
                    float x1 = acc[m][np][r] + b1;
                    float x2 = acc[m][np + 2][r] + b2;
                    long obase = ((long)((b * NH + h) * LSEQ + pos)) * 64;
                    o16[obase + d1]      = (half_t)((x1 * cv - x2 * sv) * SC);
                    o16[obase + d1 + 32] = (half_t)((x2 * cv + x1 * sv) * SC);
                }
        }
    }
}

// ---------- 4. causal flash attention, 32x32x16 MFMA, split-K ----------
// One BLOCK per (q-tile of 32, bh); its 4 waves take interleaved 64-key
// steps (flash-decoding split), each with private (m,l,O^T); merged at the
// end through LDS. S^T = mfma(K,Q) so q = lane&31; softmax per q-column
// with one xor32 reduce; P^T -> PV B-operand via 8 permlane32_swap.
__global__ __launch_bounds__(256) void attn_k(
    const half_t* __restrict__ QH, const half_t* __restrict__ KH,
    const half_t* __restrict__ VT, half_t* __restrict__ AO)
{
    __shared__ float accL[4][2][16][64];   // 32 KB
    __shared__ float mL[4][64];
    __shared__ float lL[4][64];

    const int lane = threadIdx.x & 63, wid = threadIdx.x >> 6;
    const int t  = 63 - (blockIdx.x >> 5);     // big q-tiles first
    const int bh = blockIdx.x & 31;
    const int qc = lane & 31, hi = lane >> 5;
    const int b = bh >> 4, h = bh & 15;

    const half_t* Qb = QH + ((long)bh * LSEQ + t * 32) * 64;
    const half_t* Kb = KH + (long)bh * LSEQ * 64;
    const half_t* Vb = VT + (long)bh * 64 * LSEQ;

    half8 qf[4];
#pragma unroll
    for (int dc = 0; dc < 4; ++dc)
        qf[dc] = *(const half8*)(Qb + qc * 64 + dc * 16 + hi * 8);

    f32x16 acc[2] = {};
    float m = -INFINITY, l = 0.0f;

    union PB { uint32_t u[4]; half8 h; };

    const int nsteps = (t + 2) >> 1;           // ceil((t+1)/2) 64-key steps
    const int klast = 64 * (nsteps - 1);

    for (int k0 = wid * 64; k0 < 64 * nsteps; k0 += 256) {
        const bool domask = (k0 == klast);
        // ---- loads ----
        half8 kf0[4], kf1[4], vf[2][4];
        const half_t* K0 = Kb + (long)(k0 + qc) * 64;
#pragma unroll
        for (int dc = 0; dc < 4; ++dc) {
            kf0[dc] = *(const half8*)(K0 + dc * 16 + hi * 8);
            kf1[dc] = *(const half8*)(K0 + 32 * 64 + dc * 16 + hi * 8);
        }
#pragma unroll
        for (int dt = 0; dt < 2; ++dt)
#pragma unroll
            for (int kc = 0; kc < 4; ++kc)
                vf[dt][kc] = *(const half8*)(Vb + (long)(dt * 32 + qc) * LSEQ + k0 + kc * 16 + hi * 8);

        // ---- QK^T ----
        f32x16 s0 = {}, s1 = {};
        __builtin_amdgcn_s_setprio(1);
#pragma unroll
        for (int dc = 0; dc < 4; ++dc) s0 = __builtin_amdgcn_mfma_f32_32x32x16_f16(kf0[dc], qf[dc], s0, 0, 0, 0);
#pragma unroll
        for (int dc = 0; dc < 4; ++dc) s1 = __builtin_amdgcn_mfma_f32_32x32x16_f16(kf1[dc], qf[dc], s1, 0, 0, 0);
        __builtin_amdgcn_s_setprio(0);

        if (domask) {
            int qg = t * 32 + qc;
#pragma unroll
            for (int r = 0; r < 16; ++r) {
                int crow = (r & 3) + 8 * (r >> 2) + 4 * hi;
                if (k0 + crow > qg)      s0[r] = -INFINITY;
                if (k0 + 32 + crow > qg) s1[r] = -INFINITY;
            }
        }

        // ---- online softmax (defer-max) ----
        float mx[8];
#pragma unroll
        for (int r = 0; r < 8; ++r)
            mx[r] = fmaxf(fmaxf(s0[r], s0[8 + r]), fmaxf(s1[r], s1[8 + r]));
#pragma unroll
        for (int st = 4; st >= 1; st >>= 1)
#pragma unroll
            for (int r = 0; r < 4; ++r)
                if (r < st) mx[r] = fmaxf(mx[r], mx[r + st]);
        float pm = fmaxf(mx[0], __shfl_xor(mx[0], 32, 64));
        if (__any(pm > m + 8.0f)) {            // exp2-domain threshold
            float mn = fmaxf(m, pm);
            float sc = exp2f(m - mn);
            l *= sc;
#pragma unroll
            for (int r = 0; r < 16; ++r) { acc[0][r] *= sc; acc[1][r] *= sc; }
            m = mn;
        }
#pragma unroll
        for (int r = 0; r < 16; ++r) {
            s0[r] = exp2f(s0[r] - m);
            s1[r] = exp2f(s1[r] - m);
        }
        float sm[8];
#pragma unroll
        for (int r = 0; r < 8; ++r) sm[r] = (s0[r] + s0[8 + r]) + (s1[r] + s1[8 + r]);
#pragma unroll
        for (int st = 4; st >= 1; st >>= 1)
#pragma unroll
            for (int r = 0; r < 4; ++r)
                if (r < st) sm[r] += sm[r + st];
        l += sm[0] + __shfl_xor(sm[0], 32, 64);

        // ---- pack P^T -> PV B-operand via permlane32_swap ----
        uint32_t A0[8], A1[8];
#pragma unroll
        for (int i = 0; i < 8; ++i) {
            A0[i] = pkh(s0[2 * i], s0[2 * i + 1]);
            A1[i] = pkh(s1[2 * i], s1[2 * i + 1]);
        }
        PB B00, B01, B10, B11;
        {
            auto r0 = __builtin_amdgcn_permlane32_swap(A0[0], A0[2], false, false);
            B00.u[0] = r0[0]; B00.u[2] = r0[1];
            auto r1 = __builtin_amdgcn_permlane32_swap(A0[1], A0[3], false, false);
            B00.u[1] = r1[0]; B00.u[3] = r1[1];
            auto r2 = __builtin_amdgcn_permlane32_swap(A0[4], A0[6], false, false);
            B01.u[0] = r2[0]; B01.u[2] = r2[1];
            auto r3 = __builtin_amdgcn_permlane32_swap(A0[5], A0[7], false, false);
            B01.u[1] = r3[0]; B01.u[3] = r3[1];
            auto r4 = __builtin_amdgcn_permlane32_swap(A1[0], A1[2], false, false);
            B10.u[0] = r4[0]; B10.u[2] = r4[1];
            auto r5 = __builtin_amdgcn_permlane32_swap(A1[1], A1[3], false, false);
            B10.u[1] = r5[0]; B10.u[3] = r5[1];
            auto r6 = __builtin_amdgcn_permlane32_swap(A1[4], A1[6], false, false);
            B11.u[0] = r6[0]; B11.u[2] = r6[1];
            auto r7 = __builtin_amdgcn_permlane32_swap(A1[5], A1[7], false, false);
            B11.u[1] = r7[0]; B11.u[3] = r7[1];
        }

        // ---- PV: O^T[d][q] += V^T * P ----
        __builtin_amdgcn_s_setprio(1);
#pragma unroll
        for (int dt = 0; dt < 2; ++dt) {
            acc[dt] = __builtin_amdgcn_mfma_f32_32x32x16_f16(vf[dt][0], B00.h, acc[dt], 0, 0, 0);
            acc[dt] = __builtin_amdgcn_mfma_f32_32x32x16_f16(vf[dt][1], B01.h, acc[dt], 0, 0, 0);
            acc[dt] = __builtin_amdgcn_mfma_f32_32x32x16_f16(vf[dt][2], B10.h, acc[dt], 0, 0, 0);
            acc[dt] = __builtin_amdgcn_mfma_f32_32x32x16_f16(vf[dt][3], B11.h, acc[dt], 0, 0, 0);
        }
        __builtin_amdgcn_s_setprio(0);
    }

    // ---- split-K merge through LDS ----
#pragma unroll
    for (int dt = 0; dt < 2; ++dt)
#pragma unroll
        for (int r = 0; r < 16; ++r)
            accL[wid][dt][r][lane] = acc[dt][r];
    mL[wid][lane] = m;
    lL[wid][lane] = l;
    __syncthreads();

    {
        const int dt = wid >> 1, r0 = (wid & 1) * 8;
        float m0 = mL[0][lane], m1 = mL[1][lane], m2 = mL[2][lane], m3 = mL[3][lane];
        float M = fmaxf(fmaxf(m0, m1), fmaxf(m2, m3));
        float e0 = exp2f(m0 - M), e1 = exp2f(m1 - M), e2 = exp2f(m2 - M), e3 = exp2f(m3 - M);
        float L = lL[0][lane] * e0 + lL[1][lane] * e1 + lL[2][lane] * e2 + lL[3][lane] * e3;
        float inv = 1.0f / L;
        long obase = ((long)(b * LSEQ + t * 32 + qc)) * DM + h * 64;
#pragma unroll
        for (int rg = 0; rg < 2; ++rg) {
            half4 o;
#pragma unroll
            for (int e = 0; e < 4; ++e) {
                int r = r0 + rg * 4 + e;
                float O = accL[0][dt][r][lane] * e0 + accL[1][dt][r][lane] * e1
                        + accL[2][dt][r][lane] * e2 + accL[3][dt][r][lane] * e3;
                o[e] = (half_t)(O * inv);
            }
            int rr = r0 + rg * 4;
            int d = dt * 32 + 8 * (rr >> 2) + 4 * hi;
            *(half4*)(AO + obase + d) = o;
        }
    }
}

// ---------- launch ----------
extern "C" void kernel_launch(void* const* d_in, const int* in_sizes, int n_in,
                              void* d_out, int out_size, void* d_ws, size_t ws_size,
                              hipStream_t stream) {
    const float* q  = (const float*)d_in[0];
    const float* k  = (const float*)d_in[1];
    const float* v  = (const float*)d_in[2];
    const float* wq = (const float*)d_in[4];
    const float* bq = (const float*)d_in[5];
    const float* wk = (const float*)d_in[6];
    const float* bk = (const float*)d_in[7];
    const float* wv = (const float*)d_in[8];
    const float* bv = (const float*)d_in[9];
    const float* wo = (const float*)d_in[10];
    const float* bo = (const float*)d_in[11];

    uint8_t* wsb = (uint8_t*)d_ws;
    half_t* XH = (half_t*)wsb;                       // 3 x 4194304 halfs
    half_t* WH = XH + 12582912L;                     // 4 x 1048576 halfs
    float*  COS = (float*)(wsb + 33554432L);         // 2048*32 f32
    float*  SIN = (float*)(wsb + 33816576L);
    half_t* QH = (half_t*)(wsb + 34078720L);         // [32][2048][64] f16 (scaled)
    half_t* KH = (half_t*)(wsb + 42467328L);         // [32][2048][64] f16
    half_t* VT = (half_t*)(wsb + 50855936L);         // [32][64][2048] f16
    half_t* AO = (half_t*)(wsb + 59244544L);         // [4096][1024] f16

    cvt_kernel<<<16384, 256, 0, stream>>>(q, k, v, wq, wk, wv, wo, XH);
    rope_tab<<<256, 256, 0, stream>>>(COS, SIN);

    dim3 ggrid(8, 32);
    gemm_k<0><<<ggrid, 256, 0, stream>>>(XH,             WH,             bq, QH, nullptr, COS, SIN);
    gemm_k<1><<<ggrid, 256, 0, stream>>>(XH + 4194304L,  WH + 1048576L,  bk, KH, nullptr, COS, SIN);
    gemm_k<2><<<ggrid, 256, 0, stream>>>(XH + 8388608L,  WH + 2097152L,  bv, VT, nullptr, COS, SIN);

    attn_k<<<2048, 256, 0, stream>>>(QH, KH, VT, AO);

    gemm_k<3><<<ggrid, 256, 0, stream>>>(AO, WH + 3145728L, bo, nullptr, (float*)d_out, COS, SIN);
}

// Round 4
// 164.491 us; speedup vs baseline: 2.0785x; 1.1012x over previous
//
#include <hip/hip_runtime.h>
#include <cstdint>

typedef _Float16 half_t;
using half8 = __attribute__((ext_vector_type(8))) half_t;
using half4 = __attribute__((ext_vector_type(4))) half_t;
using f32x4 = __attribute__((ext_vector_type(4))) float;
using f32x16 = __attribute__((ext_vector_type(16))) float;

#define LSEQ 2048
#define DM   1024
#define NH   16
#define DK   64

// ---------- helpers ----------
__device__ inline void gload_lds16(const void* g, void* l) {
    __builtin_amdgcn_global_load_lds(
        (const __attribute__((address_space(1))) uint32_t*)g,
        (__attribute__((address_space(3))) uint32_t*)l, 16, 0, 0);
}

__device__ inline uint32_t pkh(float a, float b) {
    half_t ha = (half_t)a, hb = (half_t)b;
    unsigned short ua = __builtin_bit_cast(unsigned short, ha);
    unsigned short ub = __builtin_bit_cast(unsigned short, hb);
    return (uint32_t)ua | ((uint32_t)ub << 16);
}

// ---------- 1. convert fp32 -> fp16 (q,k,v,Wq,Wk,Wv,Wo) ----------
__global__ __launch_bounds__(256) void cvt_kernel(
    const float* __restrict__ q, const float* __restrict__ k, const float* __restrict__ v,
    const float* __restrict__ wq, const float* __restrict__ wk,
    const float* __restrict__ wv, const float* __restrict__ wo,
    half_t* __restrict__ dst)
{
    long tid = (long)blockIdx.x * 256 + threadIdx.x;
    long e = tid * 4;
    const float* src;
    long off;
    if (e < 12582912L) {
        int a = (int)(e >> 22);
        src = (a == 0) ? q : (a == 1) ? k : v;
        off = e & 4194303L;
    } else {
        long ew = e - 12582912L;
        int w = (int)(ew >> 20);
        src = (w == 0) ? wq : (w == 1) ? wk : (w == 2) ? wv : wo;
        off = ew & 1048575L;
    }
    float4 x = *(const float4*)(src + off);
    half4 o;
    o[0] = (half_t)x.x; o[1] = (half_t)x.y; o[2] = (half_t)x.z; o[3] = (half_t)x.w;
    *(half4*)(dst + e) = o;
}

// ---------- 2. RoPE cos/sin table [2048][32] ----------
__global__ __launch_bounds__(256) void rope_tab(float* __restrict__ cosT, float* __restrict__ sinT) {
    int tid = blockIdx.x * 256 + threadIdx.x;
    int pos = tid >> 5;
    int j = tid & 31;
    float invf = powf(10000.0f, -(float)j / 32.0f);
    float a = (float)pos * invf;
    cosT[tid] = cosf(a);
    sinT[tid] = sinf(a);
}

// ---------- 3a. fused QKV projection GEMM (blockIdx.z = 0:Q 1:K 2:V) ----------
// Q/K: rope -> fragment layout QF/KF[bh][kb][dc][lane][8]; Q scaled by 1/8*log2e
// V:   fragment layout VF[bh][k64][dt][kc][lane][8]
__global__ __launch_bounds__(256) void qkv_gemm(
    const half_t* __restrict__ XH, const half_t* __restrict__ WH,
    const float* __restrict__ bq, const float* __restrict__ bk, const float* __restrict__ bv,
    half_t* __restrict__ QF, half_t* __restrict__ KF, half_t* __restrict__ VF,
    const float* __restrict__ cosT, const float* __restrict__ sinT)
{
    __shared__ alignas(16) unsigned short sA[128 * 32];
    __shared__ alignas(16) unsigned short sB[128 * 32];
    const int mode = blockIdx.z;
    const half_t* A  = XH + (long)mode * 4194304L;
    const half_t* Bw = WH + (long)mode * 1048576L;
    const float* bias = (mode == 0) ? bq : (mode == 1) ? bk : bv;

    const int tid = threadIdx.x;
    const int lane = tid & 63, wid = tid >> 6;
    const int g = lane >> 4, c = lane & 15;
    const int wr = wid >> 1, wc = wid & 1;
    const int row0 = blockIdx.y * 128, col0 = blockIdx.x * 128;

    f32x4 acc[4][4] = {};
    const int srow = lane >> 2;
    const int scol = (lane & 3) * 8;

    for (int k0 = 0; k0 < DM; k0 += 32) {
#pragma unroll
        for (int i = 0; i < 2; ++i) {
            int r = i * 64 + wid * 16;
            gload_lds16(A  + (long)(row0 + r + srow) * DM + k0 + scol, &sA[r * 32]);
            gload_lds16(Bw + (long)(col0 + r + srow) * DM + k0 + scol, &sB[r * 32]);
        }
        __syncthreads();
        half8 af[4], bf[4];
#pragma unroll
        for (int m = 0; m < 4; ++m)
            af[m] = *(const half8*)&sA[(wr * 64 + m * 16 + c) * 32 + g * 8];
#pragma unroll
        for (int n = 0; n < 4; ++n)
            bf[n] = *(const half8*)&sB[(wc * 64 + n * 16 + c) * 32 + g * 8];
#pragma unroll
        for (int m = 0; m < 4; ++m)
#pragma unroll
            for (int n = 0; n < 4; ++n)
                acc[m][n] = __builtin_amdgcn_mfma_f32_16x16x32_f16(af[m], bf[n], acc[m][n], 0, 0, 0);
        __syncthreads();
    }

    if (mode == 2) {
        const int h = blockIdx.x * 2 + wc;
#pragma unroll
        for (int n = 0; n < 4; ++n) {
            int col = col0 + wc * 64 + n * 16 + c;
            int d = n * 16 + c;
            float bvv = bias[col];
#pragma unroll
            for (int m = 0; m < 4; ++m)
#pragma unroll
                for (int r = 0; r < 4; ++r) {
                    int row = row0 + wr * 64 + m * 16 + g * 4 + r;
                    int b = row >> 11, pos = row & 2047;
                    int bh = b * NH + h;
                    long idx = (((((long)bh * 32 + (pos >> 6)) * 2 + (d >> 5)) * 4
                                 + ((pos >> 4) & 3)) * 64
                                + (((pos >> 3) & 1) * 32 + (d & 31))) * 8 + (pos & 7);
                    VF[idx] = (half_t)(acc[m][n][r] + bvv);
                }
        }
    } else {
        const float SC = (mode == 0) ? 0.125f * 1.44269504f : 1.0f;
        half_t* OF = (mode == 0) ? QF : KF;
#pragma unroll
        for (int np = 0; np < 2; ++np) {
            int col1 = col0 + wc * 64 + np * 16 + c;
            int h = col1 >> 6;
            int d1 = np * 16 + c;          // 0..31
            float b1 = bias[col1], b2 = bias[col1 + 32];
#pragma unroll
            for (int m = 0; m < 4; ++m)
#pragma unroll
                for (int r = 0; r < 4; ++r) {
                    int row = row0 + wr * 64 + m * 16 + g * 4 + r;
                    int b = row >> 11, pos = row & 2047;
                    int bh = b * NH + h;
                    float cv = cosT[pos * 32 + d1], sv = sinT[pos * 32 + d1];
                    float x1 = acc[m][np][r] + b1;
                    float x2 = acc[m][np + 2][r] + b2;
                    long kbase = ((long)(bh * 64 + (pos >> 5)) * 4) * 512
                               + ((c >> 3) * 32 + (pos & 31)) * 8 + (c & 7);
                    OF[kbase + (long)np * 512]       = (half_t)((x1 * cv - x2 * sv) * SC);
                    OF[kbase + (long)(np + 2) * 512] = (half_t)((x2 * cv + x1 * sv) * SC);
                }
        }
    }
}

// ---------- 3b. output projection GEMM ----------
__global__ __launch_bounds__(256) void out_gemm(
    const half_t* __restrict__ A, const half_t* __restrict__ Bw,
    const float* __restrict__ bias, float* __restrict__ o32)
{
    __shared__ alignas(16) unsigned short sA[128 * 32];
    __shared__ alignas(16) unsigned short sB[128 * 32];
    const int tid = threadIdx.x;
    const int lane = tid & 63, wid = tid >> 6;
    const int g = lane >> 4, c = lane & 15;
    const int wr = wid >> 1, wc = wid & 1;
    const int row0 = blockIdx.y * 128, col0 = blockIdx.x * 128;

    f32x4 acc[4][4] = {};
    const int srow = lane >> 2;
    const int scol = (lane & 3) * 8;

    for (int k0 = 0; k0 < DM; k0 += 32) {
#pragma unroll
        for (int i = 0; i < 2; ++i) {
            int r = i * 64 + wid * 16;
            gload_lds16(A  + (long)(row0 + r + srow) * DM + k0 + scol, &sA[r * 32]);
            gload_lds16(Bw + (long)(col0 + r + srow) * DM + k0 + scol, &sB[r * 32]);
        }
        __syncthreads();
        half8 af[4], bf[4];
#pragma unroll
        for (int m = 0; m < 4; ++m)
            af[m] = *(const half8*)&sA[(wr * 64 + m * 16 + c) * 32 + g * 8];
#pragma unroll
        for (int n = 0; n < 4; ++n)
            bf[n] = *(const half8*)&sB[(wc * 64 + n * 16 + c) * 32 + g * 8];
#pragma unroll
        for (int m = 0; m < 4; ++m)
#pragma unroll
            for (int n = 0; n < 4; ++n)
                acc[m][n] = __builtin_amdgcn_mfma_f32_16x16x32_f16(af[m], bf[n], acc[m][n], 0, 0, 0);
        __syncthreads();
    }
#pragma unroll
    for (int n = 0; n < 4; ++n) {
        int col = col0 + wc * 64 + n * 16 + c;
        float bv = bias[col];
#pragma unroll
        for (int m = 0; m < 4; ++m)
#pragma unroll
            for (int r = 0; r < 4; ++r) {
                int row = row0 + wr * 64 + m * 16 + g * 4 + r;
                o32[(long)row * DM + col] = acc[m][n][r] + bv;
            }
    }
}

// ---------- 4. causal flash attention, 32x32x16 MFMA, split-K ----------
// Fragment-packed inputs: every load is base + k0*64 + lane*8 (fully coalesced).
// One BLOCK per (q-tile of 32, bh); 4 waves take interleaved 64-key steps with
// private (m,l,O^T), merged through LDS. Next-K double-buffer prefetch.
__global__ __launch_bounds__(256) void attn_k(
    const half_t* __restrict__ QF, const half_t* __restrict__ KF,
    const half_t* __restrict__ VF, half_t* __restrict__ AO)
{
    __shared__ float accL[4][2][16][64];   // 32 KB
    __shared__ float mL[4][64];
    __shared__ float lL[4][64];

    const int lane = threadIdx.x & 63, wid = threadIdx.x >> 6;
    const int t  = 63 - (blockIdx.x >> 5);     // big q-tiles first
    const int bh = blockIdx.x & 31;
    const int qc = lane & 31, hi = lane >> 5;
    const int b = bh >> 4, h = bh & 15;

    const half_t* QFb = QF + (long)bh * 131072 + (long)t * 2048 + lane * 8;
    const half_t* KFb = KF + (long)bh * 131072 + lane * 8;
    const half_t* VFb = VF + (long)bh * 131072 + lane * 8;

    half8 qf[4];
#pragma unroll
    for (int dc = 0; dc < 4; ++dc)
        qf[dc] = *(const half8*)(QFb + dc * 512);

    f32x16 acc[2] = {};
    float m = -INFINITY, l = 0.0f;

    union PB { uint32_t u[4]; half8 h; };

    const int nsteps = (t + 2) >> 1;           // ceil((t+1)/2) 64-key steps
    const int klast = 64 * (nsteps - 1);
    const int kend2 = 64 * nsteps;

    auto loadK = [&](int kk, half8* a0, half8* a1) {
        const half_t* p = KFb + (long)kk * 64;
#pragma unroll
        for (int dc = 0; dc < 4; ++dc) {
            a0[dc] = *(const half8*)(p + dc * 512);
            a1[dc] = *(const half8*)(p + 2048 + dc * 512);
        }
    };

    auto step = [&](int k0, half8* ck0, half8* ck1, half8* nk0, half8* nk1) {
        // ---- V loads (issued early, used after softmax) ----
        half8 vf[2][4];
        const half_t* pv = VFb + (long)k0 * 64;
#pragma unroll
        for (int dt = 0; dt < 2; ++dt)
#pragma unroll
            for (int kc = 0; kc < 4; ++kc)
                vf[dt][kc] = *(const half8*)(pv + (dt * 4 + kc) * 512);

        // ---- prefetch next K block (hidden under softmax+PV) ----
        int kn = k0 + 256;
        if (kn < kend2) loadK(kn, nk0, nk1);

        // ---- QK^T ----
        f32x16 s0 = {}, s1 = {};
        __builtin_amdgcn_s_setprio(1);
#pragma unroll
        for (int dc = 0; dc < 4; ++dc) s0 = __builtin_amdgcn_mfma_f32_32x32x16_f16(ck0[dc], qf[dc], s0, 0, 0, 0);
#pragma unroll
        for (int dc = 0; dc < 4; ++dc) s1 = __builtin_amdgcn_mfma_f32_32x32x16_f16(ck1[dc], qf[dc], s1, 0, 0, 0);
        __builtin_amdgcn_s_setprio(0);

        if (k0 == klast) {
            int qg = t * 32 + qc;
#pragma unroll
            for (int r = 0; r < 16; ++r) {
                int crow = (r & 3) + 8 * (r >> 2) + 4 * hi;
                if (k0 + crow > qg)      s0[r] = -INFINITY;
                if (k0 + 32 + crow > qg) s1[r] = -INFINITY;
            }
        }

        // ---- online softmax (defer-max) ----
        float mx[8];
#pragma unroll
        for (int r = 0; r < 8; ++r)
            mx[r] = fmaxf(fmaxf(s0[r], s0[8 + r]), fmaxf(s1[r], s1[8 + r]));
#pragma unroll
        for (int st = 4; st >= 1; st >>= 1)
#pragma unroll
            for (int r = 0; r < 4; ++r)
                if (r < st) mx[r] = fmaxf(mx[r], mx[r + st]);
        float pm = fmaxf(mx[0], __shfl_xor(mx[0], 32, 64));
        if (__any(pm > m + 8.0f)) {            // exp2-domain threshold
            float mn = fmaxf(m, pm);
            float sc = exp2f(m - mn);
            l *= sc;
#pragma unroll
            for (int r = 0; r < 16; ++r) { acc[0][r] *= sc; acc[1][r] *= sc; }
            m = mn;
        }
#pragma unroll
        for (int r = 0; r < 16; ++r) {
            s0[r] = exp2f(s0[r] - m);
            s1[r] = exp2f(s1[r] - m);
        }
        float sm[8];
#pragma unroll
        for (int r = 0; r < 8; ++r) sm[r] = (s0[r] + s0[8 + r]) + (s1[r] + s1[8 + r]);
#pragma unroll
        for (int st = 4; st >= 1; st >>= 1)
#pragma unroll
            for (int r = 0; r < 4; ++r)
                if (r < st) sm[r] += sm[r + st];
        l += sm[0] + __shfl_xor(sm[0], 32, 64);

        // ---- pack P^T -> PV B-operand via permlane32_swap ----
        uint32_t A0[8], A1[8];
#pragma unroll
        for (int i = 0; i < 8; ++i) {
            A0[i] = pkh(s0[2 * i], s0[2 * i + 1]);
            A1[i] = pkh(s1[2 * i], s1[2 * i + 1]);
        }
        PB B00, B01, B10, B11;
        {
            auto r0 = __builtin_amdgcn_permlane32_swap(A0[0], A0[2], false, false);
            B00.u[0] = r0[0]; B00.u[2] = r0[1];
            auto r1 = __builtin_amdgcn_permlane32_swap(A0[1], A0[3], false, false);
            B00.u[1] = r1[0]; B00.u[3] = r1[1];
            auto r2 = __builtin_amdgcn_permlane32_swap(A0[4], A0[6], false, false);
            B01.u[0] = r2[0]; B01.u[2] = r2[1];
            auto r3 = __builtin_amdgcn_permlane32_swap(A0[5], A0[7], false, false);
            B01.u[1] = r3[0]; B01.u[3] = r3[1];
            auto r4 = __builtin_amdgcn_permlane32_swap(A1[0], A1[2], false, false);
            B10.u[0] = r4[0]; B10.u[2] = r4[1];
            auto r5 = __builtin_amdgcn_permlane32_swap(A1[1], A1[3], false, false);
            B10.u[1] = r5[0]; B10.u[3] = r5[1];
            auto r6 = __builtin_amdgcn_permlane32_swap(A1[4], A1[6], false, false);
            B11.u[0] = r6[0]; B11.u[2] = r6[1];
            auto r7 = __builtin_amdgcn_permlane32_swap(A1[5], A1[7], false, false);
            B11.u[1] = r7[0]; B11.u[3] = r7[1];
        }

        // ---- PV: O^T[d][q] += V^T * P ----
        __builtin_amdgcn_s_setprio(1);
#pragma unroll
        for (int dt = 0; dt < 2; ++dt) {
            acc[dt] = __builtin_amdgcn_mfma_f32_32x32x16_f16(vf[dt][0], B00.h, acc[dt], 0, 0, 0);
            acc[dt] = __builtin_amdgcn_mfma_f32_32x32x16_f16(vf[dt][1], B01.h, acc[dt], 0, 0, 0);
            acc[dt] = __builtin_amdgcn_mfma_f32_32x32x16_f16(vf[dt][2], B10.h, acc[dt], 0, 0, 0);
            acc[dt] = __builtin_amdgcn_mfma_f32_32x32x16_f16(vf[dt][3], B11.h, acc[dt], 0, 0, 0);
        }
        __builtin_amdgcn_s_setprio(0);
    };

    half8 kA0[4], kA1[4], kB0[4], kB1[4];
    int k0 = wid * 64;
    if (k0 < kend2) {
        loadK(k0, kA0, kA1);
        while (true) {
            step(k0, kA0, kA1, kB0, kB1);
            k0 += 256; if (k0 >= kend2) break;
            step(k0, kB0, kB1, kA0, kA1);
            k0 += 256; if (k0 >= kend2) break;
        }
    }

    // ---- split-K merge through LDS ----
#pragma unroll
    for (int dt = 0; dt < 2; ++dt)
#pragma unroll
        for (int r = 0; r < 16; ++r)
            accL[wid][dt][r][lane] = acc[dt][r];
    mL[wid][lane] = m;
    lL[wid][lane] = l;
    __syncthreads();

    {
        const int dt = wid >> 1, r0 = (wid & 1) * 8;
        float m0 = mL[0][lane], m1 = mL[1][lane], m2 = mL[2][lane], m3 = mL[3][lane];
        float M = fmaxf(fmaxf(m0, m1), fmaxf(m2, m3));
        float e0 = exp2f(m0 - M), e1 = exp2f(m1 - M), e2 = exp2f(m2 - M), e3 = exp2f(m3 - M);
        float L = lL[0][lane] * e0 + lL[1][lane] * e1 + lL[2][lane] * e2 + lL[3][lane] * e3;
        float inv = 1.0f / L;
        long obase = ((long)(b * LSEQ + t * 32 + qc)) * DM + h * 64;
#pragma unroll
        for (int rg = 0; rg < 2; ++rg) {
            half4 o;
#pragma unroll
            for (int e = 0; e < 4; ++e) {
                int r = r0 + rg * 4 + e;
                float O = accL[0][dt][r][lane] * e0 + accL[1][dt][r][lane] * e1
                        + accL[2][dt][r][lane] * e2 + accL[3][dt][r][lane] * e3;
                o[e] = (half_t)(O * inv);
            }
            int rr = r0 + rg * 4;
            int d = dt * 32 + 8 * (rr >> 2) + 4 * hi;
            *(half4*)(AO + obase + d) = o;
        }
    }
}

// ---------- launch ----------
extern "C" void kernel_launch(void* const* d_in, const int* in_sizes, int n_in,
                              void* d_out, int out_size, void* d_ws, size_t ws_size,
                              hipStream_t stream) {
    const float* q  = (const float*)d_in[0];
    const float* k  = (const float*)d_in[1];
    const float* v  = (const float*)d_in[2];
    const float* wq = (const float*)d_in[4];
    const float* bq = (const float*)d_in[5];
    const float* wk = (const float*)d_in[6];
    const float* bk = (const float*)d_in[7];
    const float* wv = (const float*)d_in[8];
    const float* bv = (const float*)d_in[9];
    const float* wo = (const float*)d_in[10];
    const float* bo = (const float*)d_in[11];

    uint8_t* wsb = (uint8_t*)d_ws;
    half_t* XH = (half_t*)wsb;                       // 3 x 4194304 halfs
    half_t* WH = XH + 12582912L;                     // 4 x 1048576 halfs
    float*  COS = (float*)(wsb + 33554432L);         // 2048*32 f32
    float*  SIN = (float*)(wsb + 33816576L);
    half_t* QF = (half_t*)(wsb + 34078720L);         // fragment-packed Q
    half_t* KF = (half_t*)(wsb + 42467328L);         // fragment-packed K
    half_t* VF = (half_t*)(wsb + 50855936L);         // fragment-packed V
    half_t* AO = (half_t*)(wsb + 59244544L);         // [4096][1024] f16

    cvt_kernel<<<16384, 256, 0, stream>>>(q, k, v, wq, wk, wv, wo, XH);
    rope_tab<<<256, 256, 0, stream>>>(COS, SIN);

    qkv_gemm<<<dim3(8, 32, 3), 256, 0, stream>>>(XH, WH, bq, bk, bv, QF, KF, VF, COS, SIN);

    attn_k<<<2048, 256, 0, stream>>>(QF, KF, VF, AO);

    out_gemm<<<dim3(8, 32), 256, 0, stream>>>(AO, WH + 3145728L, bo, (float*)d_out);
}

// Round 6
// 161.544 us; speedup vs baseline: 2.1164x; 1.0182x over previous
//
#include <hip/hip_runtime.h>
#include <cstdint>

typedef _Float16 half_t;
using half8 = __attribute__((ext_vector_type(8))) half_t;
using half4 = __attribute__((ext_vector_type(4))) half_t;
using f32x4 = __attribute__((ext_vector_type(4))) float;
using f32x16 = __attribute__((ext_vector_type(16))) float;

#define LSEQ 2048
#define DM   1024
#define NH   16
#define DK   64

// ---------- helpers ----------
__device__ inline void gload_lds16(const void* g, void* l) {
    __builtin_amdgcn_global_load_lds(
        (const __attribute__((address_space(1))) uint32_t*)g,
        (__attribute__((address_space(3))) uint32_t*)l, 16, 0, 0);
}

__device__ inline uint32_t pk2(float a, float b) {
    auto h = __builtin_amdgcn_cvt_pkrtz(a, b);   // v_cvt_pkrtz_f16_f32
    return __builtin_bit_cast(uint32_t, h);
}

// ---------- 1. convert fp32 -> fp16 (q,k,v,Wq,Wk,Wv,Wo) ----------
__global__ __launch_bounds__(256) void cvt_kernel(
    const float* __restrict__ q, const float* __restrict__ k, const float* __restrict__ v,
    const float* __restrict__ wq, const float* __restrict__ wk,
    const float* __restrict__ wv, const float* __restrict__ wo,
    half_t* __restrict__ dst)
{
    long tid = (long)blockIdx.x * 256 + threadIdx.x;
    long e = tid * 4;
    const float* src;
    long off;
    if (e < 12582912L) {
        int a = (int)(e >> 22);
        src = (a == 0) ? q : (a == 1) ? k : v;
        off = e & 4194303L;
    } else {
        long ew = e - 12582912L;
        int w = (int)(ew >> 20);
        src = (w == 0) ? wq : (w == 1) ? wk : (w == 2) ? wv : wo;
        off = ew & 1048575L;
    }
    float4 x = *(const float4*)(src + off);
    half4 o;
    o[0] = (half_t)x.x; o[1] = (half_t)x.y; o[2] = (half_t)x.z; o[3] = (half_t)x.w;
    *(half4*)(dst + e) = o;
}

// ---------- 2. RoPE cos/sin table [2048][32] ----------
__global__ __launch_bounds__(256) void rope_tab(float* __restrict__ cosT, float* __restrict__ sinT) {
    int tid = blockIdx.x * 256 + threadIdx.x;
    int pos = tid >> 5;
    int j = tid & 31;
    float invf = powf(10000.0f, -(float)j / 32.0f);
    float a = (float)pos * invf;
    cosT[tid] = cosf(a);
    sinT[tid] = sinf(a);
}

// ---------- 3a. fused QKV projection GEMM (blockIdx.z = 0:Q 1:K 2:V) ----------
// Q/K: rope -> fragment layout QF/KF[bh][kb][dc][lane][8]; Q scaled by 1/8*log2e
// V:   fragment layout VF[bh][k64][dt][kc][lane][8]
__global__ __launch_bounds__(256) void qkv_gemm(
    const half_t* __restrict__ XH, const half_t* __restrict__ WH,
    const float* __restrict__ bq, const float* __restrict__ bk, const float* __restrict__ bv,
    half_t* __restrict__ QF, half_t* __restrict__ KF, half_t* __restrict__ VF,
    const float* __restrict__ cosT, const float* __restrict__ sinT)
{
    __shared__ alignas(16) unsigned short sA[128 * 32];
    __shared__ alignas(16) unsigned short sB[128 * 32];
    const int mode = blockIdx.z;
    const half_t* A  = XH + (long)mode * 4194304L;
    const half_t* Bw = WH + (long)mode * 1048576L;
    const float* bias = (mode == 0) ? bq : (mode == 1) ? bk : bv;

    const int tid = threadIdx.x;
    const int lane = tid & 63, wid = tid >> 6;
    const int g = lane >> 4, c = lane & 15;
    const int wr = wid >> 1, wc = wid & 1;
    const int row0 = blockIdx.y * 128, col0 = blockIdx.x * 128;

    f32x4 acc[4][4] = {};
    const int srow = lane >> 2;
    const int scol = (lane & 3) * 8;

    for (int k0 = 0; k0 < DM; k0 += 32) {
#pragma unroll
        for (int i = 0; i < 2; ++i) {
            int r = i * 64 + wid * 16;
            gload_lds16(A  + (long)(row0 + r + srow) * DM + k0 + scol, &sA[r * 32]);
            gload_lds16(Bw + (long)(col0 + r + srow) * DM + k0 + scol, &sB[r * 32]);
        }
        __syncthreads();
        half8 af[4], bf[4];
#pragma unroll
        for (int m = 0; m < 4; ++m)
            af[m] = *(const half8*)&sA[(wr * 64 + m * 16 + c) * 32 + g * 8];
#pragma unroll
        for (int n = 0; n < 4; ++n)
            bf[n] = *(const half8*)&sB[(wc * 64 + n * 16 + c) * 32 + g * 8];
#pragma unroll
        for (int m = 0; m < 4; ++m)
#pragma unroll
            for (int n = 0; n < 4; ++n)
                acc[m][n] = __builtin_amdgcn_mfma_f32_16x16x32_f16(af[m], bf[n], acc[m][n], 0, 0, 0);
        __syncthreads();
    }

    if (mode == 2) {
        const int h = blockIdx.x * 2 + wc;
#pragma unroll
        for (int n = 0; n < 4; ++n) {
            int col = col0 + wc * 64 + n * 16 + c;
            int d = n * 16 + c;
            float bvv = bias[col];
#pragma unroll
            for (int m = 0; m < 4; ++m)
#pragma unroll
                for (int r = 0; r < 4; ++r) {
                    int row = row0 + wr * 64 + m * 16 + g * 4 + r;
                    int b = row >> 11, pos = row & 2047;
                    int bh = b * NH + h;
                    long idx = (((((long)bh * 32 + (pos >> 6)) * 2 + (d >> 5)) * 4
                                 + ((pos >> 4) & 3)) * 64
                                + (((pos >> 3) & 1) * 32 + (d & 31))) * 8 + (pos & 7);
                    VF[idx] = (half_t)(acc[m][n][r] + bvv);
                }
        }
    } else {
        const float SC = (mode == 0) ? 0.125f * 1.44269504f : 1.0f;
        half_t* OF = (mode == 0) ? QF : KF;
#pragma unroll
        for (int np = 0; np < 2; ++np) {
            int col1 = col0 + wc * 64 + np * 16 + c;
            int h = col1 >> 6;
            int d1 = np * 16 + c;          // 0..31
            float b1 = bias[col1], b2 = bias[col1 + 32];
#pragma unroll
            for (int m = 0; m < 4; ++m)
#pragma unroll
                for (int r = 0; r < 4; ++r) {
                    int row = row0 + wr * 64 + m * 16 + g * 4 + r;
                    int b = row >> 11, pos = row & 2047;
                    int bh = b * NH + h;
                    float cv = cosT[pos * 32 + d1], sv = sinT[pos * 32 + d1];
                    float x1 = acc[m][np][r] + b1;
                    float x2 = acc[m][np + 2][r] + b2;
                    long kbase = ((long)(bh * 64 + (pos >> 5)) * 4) * 512
                               + ((c >> 3) * 32 + (pos & 31)) * 8 + (c & 7);
                    OF[kbase + (long)np * 512]       = (half_t)((x1 * cv - x2 * sv) * SC);
                    OF[kbase + (long)(np + 2) * 512] = (half_t)((x2 * cv + x1 * sv) * SC);
                }
        }
    }
}

// ---------- 3b. output projection GEMM ----------
__global__ __launch_bounds__(256) void out_gemm(
    const half_t* __restrict__ A, const half_t* __restrict__ Bw,
    const float* __restrict__ bias, float* __restrict__ o32)
{
    __shared__ alignas(16) unsigned short sA[128 * 32];
    __shared__ alignas(16) unsigned short sB[128 * 32];
    const int tid = threadIdx.x;
    const int lane = tid & 63, wid = tid >> 6;
    const int g = lane >> 4, c = lane & 15;
    const int wr = wid >> 1, wc = wid & 1;
    const int row0 = blockIdx.y * 128, col0 = blockIdx.x * 128;

    f32x4 acc[4][4] = {};
    const int srow = lane >> 2;
    const int scol = (lane & 3) * 8;

    for (int k0 = 0; k0 < DM; k0 += 32) {
#pragma unroll
        for (int i = 0; i < 2; ++i) {
            int r = i * 64 + wid * 16;
            gload_lds16(A  + (long)(row0 + r + srow) * DM + k0 + scol, &sA[r * 32]);
            gload_lds16(Bw + (long)(col0 + r + srow) * DM + k0 + scol, &sB[r * 32]);
        }
        __syncthreads();
        half8 af[4], bf[4];
#pragma unroll
        for (int m = 0; m < 4; ++m)
            af[m] = *(const half8*)&sA[(wr * 64 + m * 16 + c) * 32 + g * 8];
#pragma unroll
        for (int n = 0; n < 4; ++n)
            bf[n] = *(const half8*)&sB[(wc * 64 + n * 16 + c) * 32 + g * 8];
#pragma unroll
        for (int m = 0; m < 4; ++m)
#pragma unroll
            for (int n = 0; n < 4; ++n)
                acc[m][n] = __builtin_amdgcn_mfma_f32_16x16x32_f16(af[m], bf[n], acc[m][n], 0, 0, 0);
        __syncthreads();
    }
#pragma unroll
    for (int n = 0; n < 4; ++n) {
        int col = col0 + wc * 64 + n * 16 + c;
        float bv = bias[col];
#pragma unroll
        for (int m = 0; m < 4; ++m)
#pragma unroll
            for (int r = 0; r < 4; ++r) {
                int row = row0 + wr * 64 + m * 16 + g * 4 + r;
                o32[(long)row * DM + col] = acc[m][n][r] + bv;
            }
    }
}

// ---------- 4. causal flash attention, 32x32x16 MFMA, split-K, paired tiles ----------
// Block = (pair p, bh): processes q-tile 63-p then q-tile p -> uniform ~33 steps.
// 4 waves take interleaved 64-key steps with private (m,l,O^T), LDS-merged per tile.
__global__ __launch_bounds__(256) void attn_k(
    const half_t* __restrict__ QF, const half_t* __restrict__ KF,
    const half_t* __restrict__ VF, half_t* __restrict__ AO)
{
    __shared__ float accL[4][2][16][64];   // 32 KB
    __shared__ float mL[4][64];
    __shared__ float lL[4][64];

    const int lane = threadIdx.x & 63, wid = threadIdx.x >> 6;
    const int pr = blockIdx.x >> 5;            // 0..31
    const int bh = blockIdx.x & 31;
    const int qc = lane & 31, hi = lane >> 5;
    const int b = bh >> 4, h = bh & 15;
    const int lo8 = lane * 8;

    const half_t* QU = QF + (long)bh * 131072;
    const half_t* KU = KF + (long)bh * 131072;
    const half_t* VU = VF + (long)bh * 131072;

    union PB { uint32_t u[4]; half8 h8; };

#pragma unroll 1
    for (int half_i = 0; half_i < 2; ++half_i) {
        const int t = half_i ? pr : 63 - pr;

        half8 qf[4];
        {
            const half_t* pq = QU + t * 2048;
#pragma unroll
            for (int dc = 0; dc < 4; ++dc)
                qf[dc] = *(const half8*)(pq + lo8 + dc * 512);
        }

        f32x16 acc[2] = {};
        float m = -INFINITY, l = 0.0f;

        const int nsteps = (t + 2) >> 1;
        const int klast = 64 * (nsteps - 1);
        const int kend2 = 64 * nsteps;

        auto loadK = [&](int kk, half8* a0, half8* a1) {
            const half_t* p = KU + (long)kk * 64;    // uniform part
#pragma unroll
            for (int dc = 0; dc < 4; ++dc) {
                a0[dc] = *(const half8*)(p + lo8 + dc * 512);
                a1[dc] = *(const half8*)(p + lo8 + 2048 + dc * 512);
            }
        };

        auto step = [&](int k0, half8* ck0, half8* ck1, half8* nk0, half8* nk1) {
            // ---- V loads (issued early, used after softmax) ----
            half8 vf[2][4];
            const half_t* pv = VU + (long)k0 * 64;   // uniform part
#pragma unroll
            for (int dt = 0; dt < 2; ++dt)
#pragma unroll
                for (int kc = 0; kc < 4; ++kc)
                    vf[dt][kc] = *(const half8*)(pv + lo8 + (dt * 4 + kc) * 512);

            // ---- prefetch next K block ----
            int kn = k0 + 256;
            if (kn < kend2) loadK(kn, nk0, nk1);

            // ---- QK^T ----
            f32x16 s0 = {}, s1 = {};
            __builtin_amdgcn_s_setprio(1);
#pragma unroll
            for (int dc = 0; dc < 4; ++dc) s0 = __builtin_amdgcn_mfma_f32_32x32x16_f16(ck0[dc], qf[dc], s0, 0, 0, 0);
#pragma unroll
            for (int dc = 0; dc < 4; ++dc) s1 = __builtin_amdgcn_mfma_f32_32x32x16_f16(ck1[dc], qf[dc], s1, 0, 0, 0);
            __builtin_amdgcn_s_setprio(0);

            if (k0 == klast) {
                int qg = t * 32 + qc;
#pragma unroll
                for (int r = 0; r < 16; ++r) {
                    int crow = (r & 3) + 8 * (r >> 2) + 4 * hi;
                    if (k0 + crow > qg)      s0[r] = -INFINITY;
                    if (k0 + 32 + crow > qg) s1[r] = -INFINITY;
                }
            }

            // ---- online softmax (defer-max) ----
            float t1[16];
#pragma unroll
            for (int r = 0; r < 16; ++r) t1[r] = fmaxf(s0[r], s1[r]);
#pragma unroll
            for (int st = 8; st >= 1; st >>= 1)
#pragma unroll
                for (int r = 0; r < 8; ++r)
                    if (r < st) t1[r] = fmaxf(t1[r], t1[r + st]);
            float pm = fmaxf(t1[0], __shfl_xor(t1[0], 32, 64));
            if (__any(pm > m + 8.0f)) {
                float mn = fmaxf(m, pm);
                float sc = exp2f(m - mn);
                l *= sc;
#pragma unroll
                for (int r = 0; r < 16; ++r) { acc[0][r] *= sc; acc[1][r] *= sc; }
                m = mn;
            }
#pragma unroll
            for (int r = 0; r < 16; ++r) {
                s0[r] = exp2f(s0[r] - m);
                s1[r] = exp2f(s1[r] - m);
            }
            float sm[16];
#pragma unroll
            for (int r = 0; r < 16; ++r) sm[r] = s0[r] + s1[r];
#pragma unroll
            for (int st = 8; st >= 1; st >>= 1)
#pragma unroll
                for (int r = 0; r < 8; ++r)
                    if (r < st) sm[r] += sm[r + st];
            l += sm[0] + __shfl_xor(sm[0], 32, 64);

            // ---- pack P^T -> PV B-operand (cvt_pkrtz + permlane32_swap) ----
            uint32_t A0[8], A1[8];
#pragma unroll
            for (int i = 0; i < 8; ++i) {
                A0[i] = pk2(s0[2 * i], s0[2 * i + 1]);
                A1[i] = pk2(s1[2 * i], s1[2 * i + 1]);
            }
            PB B00, B01, B10, B11;
            {
                auto r0 = __builtin_amdgcn_permlane32_swap(A0[0], A0[2], false, false);
                B00.u[0] = r0[0]; B00.u[2] = r0[1];
                auto r1 = __builtin_amdgcn_permlane32_swap(A0[1], A0[3], false, false);
                B00.u[1] = r1[0]; B00.u[3] = r1[1];
                auto r2 = __builtin_amdgcn_permlane32_swap(A0[4], A0[6], false, false);
                B01.u[0] = r2[0]; B01.u[2] = r2[1];
                auto r3 = __builtin_amdgcn_permlane32_swap(A0[5], A0[7], false, false);
                B01.u[1] = r3[0]; B01.u[3] = r3[1];
                auto r4 = __builtin_amdgcn_permlane32_swap(A1[0], A1[2], false, false);
                B10.u[0] = r4[0]; B10.u[2] = r4[1];
                auto r5 = __builtin_amdgcn_permlane32_swap(A1[1], A1[3], false, false);
                B10.u[1] = r5[0]; B10.u[3] = r5[1];
                auto r6 = __builtin_amdgcn_permlane32_swap(A1[4], A1[6], false, false);
                B11.u[0] = r6[0]; B11.u[2] = r6[1];
                auto r7 = __builtin_amdgcn_permlane32_swap(A1[5], A1[7], false, false);
                B11.u[1] = r7[0]; B11.u[3] = r7[1];
            }

            // ---- PV: O^T[d][q] += V^T * P ----
            __builtin_amdgcn_s_setprio(1);
#pragma unroll
            for (int dt = 0; dt < 2; ++dt) {
                acc[dt] = __builtin_amdgcn_mfma_f32_32x32x16_f16(vf[dt][0], B00.h8, acc[dt], 0, 0, 0);
                acc[dt] = __builtin_amdgcn_mfma_f32_32x32x16_f16(vf[dt][1], B01.h8, acc[dt], 0, 0, 0);
                acc[dt] = __builtin_amdgcn_mfma_f32_32x32x16_f16(vf[dt][2], B10.h8, acc[dt], 0, 0, 0);
                acc[dt] = __builtin_amdgcn_mfma_f32_32x32x16_f16(vf[dt][3], B11.h8, acc[dt], 0, 0, 0);
            }
            __builtin_amdgcn_s_setprio(0);
        };

        half8 kA0[4], kA1[4], kB0[4], kB1[4];
        int k0 = wid * 64;
        if (k0 < kend2) {
            loadK(k0, kA0, kA1);
            while (true) {
                step(k0, kA0, kA1, kB0, kB1);
                k0 += 256; if (k0 >= kend2) break;
                step(k0, kB0, kB1, kA0, kA1);
                k0 += 256; if (k0 >= kend2) break;
            }
        }

        // ---- split-K merge through LDS ----
#pragma unroll
        for (int dt = 0; dt < 2; ++dt)
#pragma unroll
            for (int r = 0; r < 16; ++r)
                accL[wid][dt][r][lane] = acc[dt][r];
        mL[wid][lane] = m;
        lL[wid][lane] = l;
        __syncthreads();

        {
            const int dt = wid >> 1, r0 = (wid & 1) * 8;
            float m0 = mL[0][lane], m1 = mL[1][lane], m2 = mL[2][lane], m3 = mL[3][lane];
            float M = fmaxf(fmaxf(m0, m1), fmaxf(m2, m3));
            float e0 = exp2f(m0 - M), e1 = exp2f(m1 - M), e2 = exp2f(m2 - M), e3 = exp2f(m3 - M);
            float L = lL[0][lane] * e0 + lL[1][lane] * e1 + lL[2][lane] * e2 + lL[3][lane] * e3;
            float inv = 1.0f / L;
            long obase = ((long)(b * LSEQ + t * 32 + qc)) * DM + h * 64;
#pragma unroll
            for (int rg = 0; rg < 2; ++rg) {
                half4 o;
#pragma unroll
                for (int e = 0; e < 4; ++e) {
                    int r = r0 + rg * 4 + e;
                    float O = accL[0][dt][r][lane] * e0 + accL[1][dt][r][lane] * e1
                            + accL[2][dt][r][lane] * e2 + accL[3][dt][r][lane] * e3;
                    o[e] = (half_t)(O * inv);
                }
                int rr = r0 + rg * 4;
                int d = dt * 32 + 8 * (rr >> 2) + 4 * hi;
                *(half4*)(AO + obase + d) = o;
            }
        }
        __syncthreads();   // protect LDS reuse by second tile
    }
}

// ---------- launch ----------
extern "C" void kernel_launch(void* const* d_in, const int* in_sizes, int n_in,
                              void* d_out, int out_size, void* d_ws, size_t ws_size,
                              hipStream_t stream) {
    const float* q  = (const float*)d_in[0];
    const float* k  = (const float*)d_in[1];
    const float* v  = (const float*)d_in[2];
    const float* wq = (const float*)d_in[4];
    const float* bq = (const float*)d_in[5];
    const float* wk = (const float*)d_in[6];
    const float* bk = (const float*)d_in[7];
    const float* wv = (const float*)d_in[8];
    const float* bv = (const float*)d_in[9];
    const float* wo = (const float*)d_in[10];
    const float* bo = (const float*)d_in[11];

    uint8_t* wsb = (uint8_t*)d_ws;
    half_t* XH = (half_t*)wsb;                       // 3 x 4194304 halfs
    half_t* WH = XH + 12582912L;                     // 4 x 1048576 halfs
    float*  COS = (float*)(wsb + 33554432L);         // 2048*32 f32
    float*  SIN = (float*)(wsb + 33816576L);
    half_t* QF = (half_t*)(wsb + 34078720L);         // fragment-packed Q
    half_t* KF = (half_t*)(wsb + 42467328L);         // fragment-packed K
    half_t* VF = (half_t*)(wsb + 50855936L);         // fragment-packed V
    half_t* AO = (half_t*)(wsb + 59244544L);         // [4096][1024] f16

    cvt_kernel<<<16384, 256, 0, stream>>>(q, k, v, wq, wk, wv, wo, XH);
    rope_tab<<<256, 256, 0, stream>>>(COS, SIN);

    qkv_gemm<<<dim3(8, 32, 3), 256, 0, stream>>>(XH, WH, bq, bk, bv, QF, KF, VF, COS, SIN);

    attn_k<<<1024, 256, 0, stream>>>(QF, KF, VF, AO);

    out_gemm<<<dim3(8, 32), 256, 0, stream>>>(AO, WH + 3145728L, bo, (float*)d_out);
}